// Round 8
// baseline (273.060 us; speedup 1.0000x reference)
//
#include <hip/hip_runtime.h>
#include <math.h>

#define BSZ  32
#define GSZ  50
#define ATOT 8400
#define NCLS 80
#define CDIM 85
#define TPB  256
#define GRIDX ((ATOT + TPB - 1) / TPB)      // 33
#define NPART (GRIDX * BSZ)                 // 1056
#define MAXC 512                            // max or_m candidates per (gt,img)

// decode chunk-block layout: p8: 32 b x 17 chunks(5ch) = 544; p16: 32 x 5 chunks(17ch) = 160;
// p32: 32 x 1 chunk(85ch) = 32; +1 prep block
#define NB8   544
#define NB16  160
#define NB32  32
#define DECGRID (NB8 + NB16 + NB32 + 1)     // 737

#define EPSF 1e-7f
#define BIGF 100000.0f
#define INFF 1000000000.0f
#define IMGF 640.0f
#define DISF 20.0f        // 2.5 * stride(8)
#define LOGEPS_HI -15.942385f   // logf(2^-23) = ref log(1 - (1-eps)) floor

__device__ __forceinline__ float sigm(float z){ return 1.0f/(1.0f+expf(-z)); }
__device__ __forceinline__ float clampp(float s){ return fminf(fmaxf(s, EPSF), 1.f-EPSF); }
// log(1 - clip(sigmoid(z))) via softplus identity (exact in the unclamped range)
__device__ __forceinline__ float log1msig(float z){
  return fmaxf(-logf(1.f + expf(z)), LOGEPS_HI);
}

__device__ __forceinline__ const float* chan_ptr(const float* __restrict__ p8,
                                                 const float* __restrict__ p16,
                                                 const float* __restrict__ p32,
                                                 int b, int a, int ch){
  if (a < 6400) return p8  + ((size_t)(b*CDIM + ch))*6400 + a;
  if (a < 8000) return p16 + ((size_t)(b*CDIM + ch))*1600 + (a-6400);
  return p32 + ((size_t)(b*CDIM + ch))*400 + (a-8000);
}

// cost/iou for one (gt, anchor) pair; clsc via logit identity: log(1-s)-log(s) = -z
__device__ __forceinline__ void compute_pair(
  float cx, float cy, float gw, float gh,
  float px, float py, float pw, float ph,
  float z, float slog,
  float& cost, float& iou, bool& orm, bool& andm, float& clsc)
{
  float hw = gw*0.5f, hh = gh*0.5f;
  bool cm = (px >= fmaxf(cx-DISF,0.f)) && (px <= fminf(cx+DISF,IMGF)) &&
            (py >= fmaxf(cy-DISF,0.f)) && (py <= fminf(cy+DISF,IMGF));
  bool im = (px >= fmaxf(cx-hw,0.f)) && (px <= fminf(cx+hw,IMGF)) &&
            (py >= fmaxf(cy-hh,0.f)) && (py <= fminf(cy+hh,IMGF));
  orm = cm || im;  andm = cm && im;
  float phw = pw*0.5f, phh = ph*0.5f;
  float wx = fmaxf(fminf(cx+hw, px+phw) - fmaxf(cx-hw, px-phw), 0.f);
  float wy = fmaxf(fminf(cy+hh, py+phh) - fmaxf(cy-hh, py-phh), 0.f);
  float inter = wx*wy;
  float uni   = gw*gh + pw*ph - inter;
  iou = inter / fmaxf(uni, 1e-6f);
  clsc = -z - slog;
  cost = clsc + 3.f*(-logf(iou + 1e-8f)) + (andm ? 0.f : BIGF);
}

// ---- streaming chunk decoder: reads channels [C0, C0+NCH) of one (b,level)
// plane LINEARLY (float4, memory order). Class channels accumulate log1msig
// into LDS slog tile; box channels transform-and-store. LDS tile flushed via
// fire-and-forget global float atomicAdds (slog pre-zeroed by hipMemsetAsync).
template<int L, int AOFF, int FSI>
__device__ __forceinline__ void decode_chunk(
  const float* __restrict__ plane, int b, int C0, int NCH,
  float* __restrict__ bx, float* __restrict__ by,
  float* __restrict__ bw, float* __restrict__ bh,
  float* __restrict__ obj, float* __restrict__ slog,
  float* __restrict__ lds)
{
  constexpr int L2 = L*L;
  constexpr int Q  = L2/4;                 // float4s per channel (L%4==0 for all levels... L=20,40,80 ok; 20*20=400/4=100)
  const float FS = (float)FSI;
  const float4* p4 = (const float4*)plane;
  bool has_cls = (C0 + NCH) > 5;
  if (has_cls){
    for (int a = threadIdx.x; a < L2; a += TPB) lds[a] = 0.f;
    __syncthreads();
  }
  const int NF = NCH * Q;
  for (int f = threadIdx.x; f < NF; f += TPB){
    int fq = C0*Q + f;                     // global float4 index in plane (linear)
    int c  = fq / Q;                       // const-div (Q compile-time)
    int r  = fq - c*Q;
    int a  = r*4;
    float4 v = p4[fq];
    if (c >= 5){
      atomicAdd(&lds[a+0], log1msig(v.x));
      atomicAdd(&lds[a+1], log1msig(v.y));
      atomicAdd(&lds[a+2], log1msig(v.z));
      atomicAdd(&lds[a+3], log1msig(v.w));
    } else {
      int gidx = (int)(((size_t)b*ATOT + AOFF + a) >> 2);
      if (c == 0){
        int i = a / L; int j = a - i*L;    // row-contiguous: L%4==0
        ((float4*)bx)[gidx] = make_float4(((float)(j  )+sigm(v.x))*FS,
                                          ((float)(j+1)+sigm(v.y))*FS,
                                          ((float)(j+2)+sigm(v.z))*FS,
                                          ((float)(j+3)+sigm(v.w))*FS);
      } else if (c == 1){
        float fi = (float)(a / L);
        ((float4*)by)[gidx] = make_float4((fi+sigm(v.x))*FS, (fi+sigm(v.y))*FS,
                                          (fi+sigm(v.z))*FS, (fi+sigm(v.w))*FS);
      } else if (c == 2){
        ((float4*)bw)[gidx] = make_float4(expf(v.x)*FS, expf(v.y)*FS,
                                          expf(v.z)*FS, expf(v.w)*FS);
      } else if (c == 3){
        ((float4*)bh)[gidx] = make_float4(expf(v.x)*FS, expf(v.y)*FS,
                                          expf(v.z)*FS, expf(v.w)*FS);
      } else {
        ((float4*)obj)[gidx] = make_float4(sigm(v.x), sigm(v.y), sigm(v.z), sigm(v.w));
      }
    }
  }
  if (has_cls){
    __syncthreads();
    float* dst = slog + (size_t)b*ATOT + AOFF;
    for (int a = threadIdx.x; a < L2; a += TPB)
      atomicAdd(&dst[a], lds[a]);          // no-return global_atomic_add_f32
  }
}

// ---- K-decode: 736 streaming chunk blocks + 1 prep block (per-gt argmax)
__global__ void k_decode(const float* __restrict__ p8, const float* __restrict__ p16,
                         const float* __restrict__ p32, const float* __restrict__ tgt,
                         float* __restrict__ bx, float* __restrict__ by,
                         float* __restrict__ bw, float* __restrict__ bh,
                         float* __restrict__ obj, float* __restrict__ slog,
                         int* __restrict__ cidx){
  __shared__ float lds[6400];
  int id = blockIdx.x;
  if (id < NB8){
    int b = id / 17, ch = id % 17;         // chunk = 5 channels; chunk0 = boxes
    decode_chunk<80, 0, 8>(p8 + (size_t)b*CDIM*6400, b, ch*5, 5,
                           bx, by, bw, bh, obj, slog, lds);
  } else if (id < NB8 + NB16){
    int id2 = id - NB8;
    int b = id2 / 5, ch = id2 % 5;         // chunk = 17 channels
    decode_chunk<40, 6400, 16>(p16 + (size_t)b*CDIM*1600, b, ch*17, 17,
                               bx, by, bw, bh, obj, slog, lds);
  } else if (id < NB8 + NB16 + NB32){
    int b = id - NB8 - NB16;               // whole plane
    decode_chunk<20, 8000, 32>(p32 + (size_t)b*CDIM*400, b, 0, 85,
                               bx, by, bw, bh, obj, slog, lds);
  } else {                                 // fused k_prep
    for (int t = threadIdx.x; t < BSZ*GSZ; t += TPB){
      const float* T = tgt + (size_t)t*CDIM;
      int best = 0; float bv = T[5];
      for (int c = 1; c < NCLS; c++){
        float v = T[5+c];
        if (v > bv){ bv = v; best = c; }
      }
      cidx[t] = best;
    }
  }
}

// ---- K-assign: one block per (gt g, image b); two-phase LDS compaction
__global__ void k_assign(const float* __restrict__ p8, const float* __restrict__ p16,
                         const float* __restrict__ p32, const float* __restrict__ tgt,
                         const int* __restrict__ cidx,
                         const float* __restrict__ bx, const float* __restrict__ by,
                         const float* __restrict__ bw, const float* __restrict__ bh,
                         const float* __restrict__ slog,
                         unsigned long long* __restrict__ bits){
  int g = blockIdx.x, b = blockIdx.y;
  const float* T = tgt + ((size_t)b*GSZ + g)*CDIM;
  if (T[4] != 1.0f) return;                 // uniform for whole block
  float cx = T[0], cy = T[1], gw = T[2], gh = T[3];
  float hw = gw*0.5f, hh = gh*0.5f;
  float cL = fmaxf(cx-DISF,0.f), cR = fminf(cx+DISF,IMGF);
  float cT = fmaxf(cy-DISF,0.f), cB = fminf(cy+DISF,IMGF);
  float iL = fmaxf(cx-hw,0.f),  iR = fminf(cx+hw,IMGF);
  float iT = fmaxf(cy-hh,0.f),  iB = fminf(cy+hh,IMGF);
  float gArea = gw*gh;
  int ch = 5 + cidx[b*GSZ + g];
  int t = threadIdx.x;
  int lane = t & 63, wave = t >> 6;

  const float* BX = bx + (size_t)b*ATOT;
  const float* BY = by + (size_t)b*ATOT;
  const float* BW = bw + (size_t)b*ATOT;
  const float* BH = bh + (size_t)b*ATOT;
  const float* SL = slog + (size_t)b*ATOT;

  // ---- phase A: mask-only scan, compact or_m candidates into LDS
  __shared__ int cand[MAXC];
  __shared__ int ncand_sh, nand_sh;
  if (t == 0){ ncand_sh = 0; nand_sh = 0; }
  __syncthreads();
  for (int a = t; a < ATOT; a += TPB){
    float px = BX[a], py = BY[a];
    bool cm = (px >= cL) && (px <= cR) && (py >= cT) && (py <= cB);
    bool im = (px >= iL) && (px <= iR) && (py >= iT) && (py <= iB);
    if (cm || im){
      int pos = atomicAdd(&ncand_sh, 1);
      if (pos < MAXC) cand[pos] = a | ((cm && im) ? 0x10000 : 0);
      if (cm && im) atomicAdd(&nand_sh, 1);
    }
  }
  __syncthreads();
  int nc = ncand_sh < MAXC ? ncand_sh : MAXC;
  int and_cnt = nand_sh;

  // ---- phase B: dense candidate processing (all gathers issue in parallel)
  float lc[10]; int li[10]; float lio[10];
  #pragma unroll
  for (int k = 0; k < 10; k++){ lc[k] = 3.0e38f; li[k] = -1; lio[k] = -1.f; }

  for (int c = t; c < nc; c += TPB){
    int packed = cand[c];
    int a = packed & 0xFFFF;
    bool andm = (packed & 0x10000) != 0;
    float px = BX[a], py = BY[a];
    float pw = BW[a], ph = BH[a];
    float phw = pw*0.5f, phh = ph*0.5f;
    float wx = fmaxf(fminf(cx+hw, px+phw) - fmaxf(cx-hw, px-phw), 0.f);
    float wy = fmaxf(fminf(cy+hh, py+phh) - fmaxf(cy-hh, py-phh), 0.f);
    float inter = wx*wy;
    float iou = inter / fmaxf(gArea + pw*ph - inter, 1e-6f);
    float z = *chan_ptr(p8, p16, p32, b, a, ch);
    float clsc = -z - SL[a];                // logit identity, no exp/log
    float cost = clsc + 3.f*(-logf(iou + 1e-8f)) + (andm ? 0.f : BIGF);
    {   // lexicographic (cost, idx) insertion — order-independent & stable
      float v = cost; int vi = a;
      #pragma unroll
      for (int k = 0; k < 10; k++){
        if (v < lc[k] || (v == lc[k] && (unsigned)vi < (unsigned)li[k])){
          float tv = lc[k]; int ti = li[k];
          lc[k] = v; li[k] = vi; v = tv; vi = ti;
        }
      }
    }
    if (iou > lio[9]){
      float v = iou;
      #pragma unroll
      for (int k = 0; k < 10; k++){
        if (v > lio[k]){ float tv = lio[k]; lio[k] = v; v = tv; }
      }
    }
  }

  // ---- wave-level merge (no barriers): 10 rounds of 64-lane butterfly
  float mc[10]; int mi[10]; float mio[10];
  {
    int hp = 0;
    #pragma unroll
    for (int r = 0; r < 10; r++){
      float v  = (hp < 10) ? lc[hp] : 3.4e38f;
      int  idx = (hp < 10) ? li[hp] : -1;
      int  wl  = lane;
      #pragma unroll
      for (int s2 = 32; s2 > 0; s2 >>= 1){
        float v2 = __shfl_xor(v, s2, 64);
        int   i2 = __shfl_xor(idx, s2, 64);
        int   l2 = __shfl_xor(wl, s2, 64);
        if (v2 < v || (v2 == v && (unsigned)i2 < (unsigned)idx)){
          v = v2; idx = i2; wl = l2;
        }
      }
      mc[r] = v; mi[r] = idx;
      if (lane == wl) hp++;
    }
    int hq = 0;
    #pragma unroll
    for (int r = 0; r < 10; r++){
      float v = (hq < 10) ? lio[hq] : -2.f;
      int  wl = lane;
      #pragma unroll
      for (int s2 = 32; s2 > 0; s2 >>= 1){
        float v2 = __shfl_xor(v, s2, 64);
        int   l2 = __shfl_xor(wl, s2, 64);
        if (v2 > v || (v2 == v && l2 < wl)){ v = v2; wl = l2; }
      }
      mio[r] = v;
      if (lane == wl) hq++;
    }
  }

  __shared__ float smc[4*10]; __shared__ int smi[4*10]; __shared__ float smio[4*10];
  if (lane == 0){
    #pragma unroll
    for (int k = 0; k < 10; k++){
      smc[wave*10+k] = mc[k]; smi[wave*10+k] = mi[k]; smio[wave*10+k] = mio[k];
    }
  }
  __syncthreads();

  if (t == 0){
    float k10 = 0.f;
    {
      int h[4] = {0,0,0,0};
      for (int r = 0; r < 10; r++){
        float v = -2.f; int w = -1;
        for (int q = 0; q < 4; q++){
          if (h[q] < 10){
            float vq = smio[q*10+h[q]];
            if (vq > v){ v = vq; w = q; }
          }
        }
        if (w >= 0) h[w]++;
        k10 += fmaxf(v, 0.f);               // iou*or_m: empties contribute 0
      }
    }
    int dk = (int)k10;
    if (dk < 1) dk = 1;
    int ub = and_cnt > 1 ? and_cnt : 1;
    if (dk > ub) dk = ub;
    int h[4] = {0,0,0,0};
    for (int r = 0; r < dk && r < 10; r++){
      float v = 3.4e38f; int idx = -1; int w = -1;
      for (int q = 0; q < 4; q++){
        if (h[q] < 10){
          float vq = smc[q*10+h[q]]; int iq = smi[q*10+h[q]];
          if (vq < v || (vq == v && (unsigned)iq < (unsigned)idx)){
            v = vq; idx = iq; w = q;
          }
        }
      }
      if (idx < 0) break;                   // fewer than dk or_m anchors
      h[w]++;
      atomicOr(&bits[(size_t)b*ATOT + idx], 1ull << g);
    }
  }
}

// ---- K-loss: overlap resolution + conf/cls/reg losses -> per-block partial
__global__ void k_loss(const float* __restrict__ p8, const float* __restrict__ p16,
                       const float* __restrict__ p32, const float* __restrict__ tgt,
                       const int* __restrict__ cidx,
                       const float* __restrict__ bx, const float* __restrict__ by,
                       const float* __restrict__ bw, const float* __restrict__ bh,
                       const float* __restrict__ obj, const float* __restrict__ slog,
                       const unsigned long long* __restrict__ bits,
                       float* __restrict__ partials){
  int b = blockIdx.y;
  int a = blockIdx.x*TPB + threadIdx.x;
  __shared__ float gcx[GSZ], gcy[GSZ], ggw[GSZ], ggh[GSZ], gval[GSZ];
  __shared__ int gci[GSZ];
  for (int k = threadIdx.x; k < GSZ; k += TPB){
    const float* T = tgt + ((size_t)b*GSZ + k)*CDIM;
    gcx[k] = T[0]; gcy[k] = T[1]; ggw[k] = T[2]; ggh[k] = T[3]; gval[k] = T[4];
    gci[k] = cidx[b*GSZ + k];
  }
  __syncthreads();

  float contrib = 0.f;
  if (a < ATOT){
    size_t t = (size_t)b*ATOT + a;
    unsigned long long m = bits[t];
    float px = bx[t], py = by[t], pw = bw[t], ph = bh[t], sl = slog[t];
    if (__builtin_popcountll(m) > 1){
      float bestc = INFF; int bestg = 0;
      for (int g = 0; g < GSZ; g++){
        float c = INFF;
        if (gval[g] == 1.0f){
          float z = *chan_ptr(p8, p16, p32, b, a, 5+gci[g]);
          float iou, clsc; bool orm, andm;
          compute_pair(gcx[g], gcy[g], ggw[g], ggh[g], px, py, pw, ph, z, sl,
                       c, iou, orm, andm, clsc);
        }
        if (c < bestc){ bestc = c; bestg = g; }
      }
      m = 1ull << bestg;
    }
    bool fg = (m != 0ull);
    float o = clampp(obj[t]);
    contrib = fg ? -logf(o) : -logf(1.f - o);     // conf BCE
    while (m){
      int g = __builtin_ctzll(m);
      m &= m - 1;
      float z = *chan_ptr(p8, p16, p32, b, a, 5+gci[g]);
      float c, iou, clsc; bool orm, andm;
      compute_pair(gcx[g], gcy[g], ggw[g], ggh[g], px, py, pw, ph, z, sl,
                   c, iou, orm, andm, clsc);
      contrib += clsc + 5.f*(1.f - iou*iou);      // l_cls + reg_weight*l_reg
    }
  }

  // wave reduce, then 4 wave-sums via LDS, single global store (NO atomics)
  #pragma unroll
  for (int s2 = 32; s2 > 0; s2 >>= 1) contrib += __shfl_xor(contrib, s2, 64);
  __shared__ float wsum[4];
  if ((threadIdx.x & 63) == 0) wsum[threadIdx.x >> 6] = contrib;
  __syncthreads();
  if (threadIdx.x == 0)
    partials[blockIdx.y*GRIDX + blockIdx.x] = wsum[0]+wsum[1]+wsum[2]+wsum[3];
}

// ---- K-final: reduce 1056 partials + count valid gts + divide
__global__ void k_final(const float* __restrict__ partials,
                        const float* __restrict__ tgt, float* __restrict__ out){
  int t = threadIdx.x;
  float s = 0.f;
  for (int i = t; i < NPART; i += TPB) s += partials[i];
  int n = 0;
  for (int i = t; i < BSZ*GSZ; i += TPB)
    n += (tgt[(size_t)i*CDIM + 4] == 1.0f) ? 1 : 0;
  __shared__ float sh[TPB]; __shared__ int shn[TPB];
  sh[t] = s; shn[t] = n;
  __syncthreads();
  for (int st = TPB/2; st > 0; st >>= 1){
    if (t < st){ sh[t] += sh[t+st]; shn[t] += shn[t+st]; }
    __syncthreads();
  }
  if (t == 0){
    int nn = shn[0] < 1 ? 1 : shn[0];
    out[0] = sh[0] / (float)nn;
  }
}

extern "C" void kernel_launch(void* const* d_in, const int* in_sizes, int n_in,
                              void* d_out, int out_size, void* d_ws, size_t ws_size,
                              hipStream_t stream) {
  const float* p8  = (const float*)d_in[0];
  const float* p16 = (const float*)d_in[1];
  const float* p32 = (const float*)d_in[2];
  const float* tgt = (const float*)d_in[3];
  float* out = (float*)d_out;

  const size_t BA = (size_t)BSZ*ATOT;
  float* bx   = (float*)d_ws;
  float* by   = bx + BA;
  float* bw   = by + BA;
  float* bh   = bw + BA;
  float* obj  = bh + BA;
  float* slog = obj + BA;
  unsigned long long* bits = (unsigned long long*)(slog + BA);  // adjacent to slog
  int* cidx = (int*)(bits + BA);
  float* partials = (float*)(cidx + BSZ*GSZ);

  dim3 blk(TPB);
  // zero slog (atomic-accumulated) + bits (assignment masks) in one memset
  hipMemsetAsync(slog, 0, BA*4 + BA*8, stream);
  k_decode<<<dim3(DECGRID), blk, 0, stream>>>(p8, p16, p32, tgt,
                                              bx, by, bw, bh, obj, slog, cidx);
  k_assign<<<dim3(GSZ, BSZ), blk, 0, stream>>>(p8, p16, p32, tgt, cidx,
                                               bx, by, bw, bh, slog, bits);
  k_loss  <<<dim3(GRIDX, BSZ), blk, 0, stream>>>(p8, p16, p32, tgt, cidx,
                                               bx, by, bw, bh, obj, slog, bits, partials);
  k_final <<<1, blk, 0, stream>>>(partials, tgt, out);
}

// Round 9
// 188.732 us; speedup vs baseline: 1.4468x; 1.4468x over previous
//
#include <hip/hip_runtime.h>
#include <math.h>

#define BSZ  32
#define GSZ  50
#define ATOT 8400
#define NCLS 80
#define CDIM 85
#define TPB  256
#define GRIDX ((ATOT + TPB - 1) / TPB)      // 33
#define NPART (GRIDX * BSZ)                 // 1056
#define MAXC 512                            // max or_m candidates per (gt,img); bound ~456

#define EPSF 1e-7f
#define BIGF 100000.0f
#define INFF 1000000000.0f
#define IMGF 640.0f
#define DISF 20.0f        // 2.5 * stride(8)
#define LOGEPS_HI -15.942385f   // logf(2^-23) = ref log(1 - (1-eps)) floor

__device__ __forceinline__ float sigm(float z){ return 1.0f/(1.0f+expf(-z)); }
__device__ __forceinline__ float clampp(float s){ return fminf(fmaxf(s, EPSF), 1.f-EPSF); }
// log(1 - clip(sigmoid(z))) via softplus identity (exact in the unclamped range)
__device__ __forceinline__ float log1msig(float z){
  return fmaxf(-logf(1.f + expf(z)), LOGEPS_HI);
}

__device__ __forceinline__ const float* chan_ptr(const float* __restrict__ p8,
                                                 const float* __restrict__ p16,
                                                 const float* __restrict__ p32,
                                                 int b, int a, int ch){
  if (a < 6400) return p8  + ((size_t)(b*CDIM + ch))*6400 + a;
  if (a < 8000) return p16 + ((size_t)(b*CDIM + ch))*1600 + (a-6400);
  return p32 + ((size_t)(b*CDIM + ch))*400 + (a-8000);
}

// cost/iou for one (gt, anchor) pair; clsc via logit identity: log(1-s)-log(s) = -z
__device__ __forceinline__ void compute_pair(
  float cx, float cy, float gw, float gh,
  float px, float py, float pw, float ph,
  float z, float slog,
  float& cost, float& iou, bool& orm, bool& andm, float& clsc)
{
  float hw = gw*0.5f, hh = gh*0.5f;
  bool cm = (px >= fmaxf(cx-DISF,0.f)) && (px <= fminf(cx+DISF,IMGF)) &&
            (py >= fmaxf(cy-DISF,0.f)) && (py <= fminf(cy+DISF,IMGF));
  bool im = (px >= fmaxf(cx-hw,0.f)) && (px <= fminf(cx+hw,IMGF)) &&
            (py >= fmaxf(cy-hh,0.f)) && (py <= fminf(cy+hh,IMGF));
  orm = cm || im;  andm = cm && im;
  float phw = pw*0.5f, phh = ph*0.5f;
  float wx = fmaxf(fminf(cx+hw, px+phw) - fmaxf(cx-hw, px-phw), 0.f);
  float wy = fmaxf(fminf(cy+hh, py+phh) - fmaxf(cy-hh, py-phh), 0.f);
  float inter = wx*wy;
  float uni   = gw*gh + pw*ph - inter;
  iou = inter / fmaxf(uni, 1e-6f);
  clsc = -z - slog;
  cost = clsc + 3.f*(-logf(iou + 1e-8f)) + (andm ? 0.f : BIGF);
}

// ---- K-prep: per-gt class index (one-hot argmax)
__global__ void k_prep(const float* __restrict__ tgt, int* __restrict__ cidx){
  int t = blockIdx.x*blockDim.x + threadIdx.x;
  if (t >= BSZ*GSZ) return;
  const float* T = tgt + (size_t)t*CDIM;
  int best = 0; float bv = T[5];
  for (int c = 1; c < NCLS; c++){
    float v = T[5+c];
    if (v > bv){ bv = v; best = c; }
  }
  cidx[t] = best;
}

// ---- K-decode: 4 threads per float4-group (each owns 20 cls channels + 1 box ch).
// Per-wave load pattern: 16 groups x 4 channels -> 4 segments of 256 B.
// [r6/r8 lessons: 8-thread split (128B segments) and streaming+LDS-atomics both
//  regressed; this layout is the best measured.]
__global__ void k_decode(const float* __restrict__ p8, const float* __restrict__ p16,
                         const float* __restrict__ p32,
                         float* __restrict__ bx, float* __restrict__ by,
                         float* __restrict__ bw, float* __restrict__ bh,
                         float* __restrict__ obj, float* __restrict__ slog,
                         unsigned long long* __restrict__ bits){
  int t = blockIdx.x*blockDim.x + threadIdx.x;   // exactly BSZ*ATOT threads
  int sub = t & 3;
  int g   = t >> 2;                               // float4-group id
  int b = g / (ATOT/4);
  int q = g % (ATOT/4);
  int a0 = q*4;                                   // level edges 6400/8000 are /4
  const float* base; int l; float fs; int aL;
  if (a0 < 6400){ base = p8;  l = 80; fs = 8.f;  aL = a0; }
  else if (a0 < 8000){ base = p16; l = 40; fs = 16.f; aL = a0-6400; }
  else { base = p32; l = 20; fs = 32.f; aL = a0-8000; }
  int l2 = l*l;
  int cs = l2 >> 2;                               // channel stride in float4
  const float4* p4 = (const float4*)(base + (size_t)b*CDIM*l2) + (aL >> 2);

  // partial slog over this sub's class channels (5+sub, step 4 -> 20 channels)
  float4 S = make_float4(0.f,0.f,0.f,0.f);
  for (int c = 5+sub; c < CDIM; c += 4){
    float4 v = p4[c*cs];
    S.x += log1msig(v.x); S.y += log1msig(v.y);
    S.z += log1msig(v.z); S.w += log1msig(v.w);
  }
  // reduce across the 4 consecutive lanes of this group (same wave: 4 | 64)
  #pragma unroll
  for (int m = 1; m <= 2; m <<= 1){
    S.x += __shfl_xor(S.x, m, 64);
    S.y += __shfl_xor(S.y, m, 64);
    S.z += __shfl_xor(S.z, m, 64);
    S.w += __shfl_xor(S.w, m, 64);
  }

  int i = aL / l, j = aL % l;
  float fi = (float)i;
  uint4 z4 = make_uint4(0u,0u,0u,0u);
  if (sub == 0){
    float4 v0 = p4[0];
    float4 v4 = p4[4*cs];
    ((float4*)bx)[g]  = make_float4(((float)(j  )+sigm(v0.x))*fs, ((float)(j+1)+sigm(v0.y))*fs,
                                    ((float)(j+2)+sigm(v0.z))*fs, ((float)(j+3)+sigm(v0.w))*fs);
    ((float4*)obj)[g] = make_float4(sigm(v4.x), sigm(v4.y), sigm(v4.z), sigm(v4.w));
    ((uint4*)bits)[2*g] = z4;                     // zero 2 of 4 u64 masks
  } else if (sub == 1){
    float4 v1 = p4[cs];
    ((float4*)by)[g]   = make_float4((fi+sigm(v1.x))*fs, (fi+sigm(v1.y))*fs,
                                     (fi+sigm(v1.z))*fs, (fi+sigm(v1.w))*fs);
    ((float4*)slog)[g] = S;
  } else if (sub == 2){
    float4 v2 = p4[2*cs];
    ((float4*)bw)[g] = make_float4(expf(v2.x)*fs, expf(v2.y)*fs, expf(v2.z)*fs, expf(v2.w)*fs);
    ((uint4*)bits)[2*g+1] = z4;
  } else {
    float4 v3 = p4[3*cs];
    ((float4*)bh)[g] = make_float4(expf(v3.x)*fs, expf(v3.y)*fs, expf(v3.z)*fs, expf(v3.w)*fs);
  }
}

// ---- K-assign: one block per (gt g, image b); two-phase LDS compaction
__global__ void k_assign(const float* __restrict__ p8, const float* __restrict__ p16,
                         const float* __restrict__ p32, const float* __restrict__ tgt,
                         const int* __restrict__ cidx,
                         const float* __restrict__ bx, const float* __restrict__ by,
                         const float* __restrict__ bw, const float* __restrict__ bh,
                         const float* __restrict__ slog,
                         unsigned long long* __restrict__ bits){
  int g = blockIdx.x, b = blockIdx.y;
  const float* T = tgt + ((size_t)b*GSZ + g)*CDIM;
  if (T[4] != 1.0f) return;                 // uniform for whole block
  float cx = T[0], cy = T[1], gw = T[2], gh = T[3];
  float hw = gw*0.5f, hh = gh*0.5f;
  float cL = fmaxf(cx-DISF,0.f), cR = fminf(cx+DISF,IMGF);
  float cT = fmaxf(cy-DISF,0.f), cB = fminf(cy+DISF,IMGF);
  float iL = fmaxf(cx-hw,0.f),  iR = fminf(cx+hw,IMGF);
  float iT = fmaxf(cy-hh,0.f),  iB = fminf(cy+hh,IMGF);
  float gArea = gw*gh;
  int ch = 5 + cidx[b*GSZ + g];
  int t = threadIdx.x;
  int lane = t & 63, wave = t >> 6;

  const float* BX = bx + (size_t)b*ATOT;
  const float* BY = by + (size_t)b*ATOT;
  const float* BW = bw + (size_t)b*ATOT;
  const float* BH = bh + (size_t)b*ATOT;
  const float* SL = slog + (size_t)b*ATOT;

  // ---- phase A: mask-only scan, compact or_m candidates into LDS
  __shared__ int cand[MAXC];
  __shared__ int ncand_sh, nand_sh;
  if (t == 0){ ncand_sh = 0; nand_sh = 0; }
  __syncthreads();
  for (int a = t; a < ATOT; a += TPB){
    float px = BX[a], py = BY[a];
    bool cm = (px >= cL) && (px <= cR) && (py >= cT) && (py <= cB);
    bool im = (px >= iL) && (px <= iR) && (py >= iT) && (py <= iB);
    if (cm || im){
      int pos = atomicAdd(&ncand_sh, 1);
      if (pos < MAXC) cand[pos] = a | ((cm && im) ? 0x10000 : 0);
      if (cm && im) atomicAdd(&nand_sh, 1);
    }
  }
  __syncthreads();
  int nc = ncand_sh < MAXC ? ncand_sh : MAXC;
  int and_cnt = nand_sh;

  // ---- phase B: dense candidate processing (all gathers issue in parallel)
  float lc[10]; int li[10]; float lio[10];
  #pragma unroll
  for (int k = 0; k < 10; k++){ lc[k] = 3.0e38f; li[k] = -1; lio[k] = -1.f; }

  for (int c = t; c < nc; c += TPB){
    int packed = cand[c];
    int a = packed & 0xFFFF;
    bool andm = (packed & 0x10000) != 0;
    float px = BX[a], py = BY[a];
    float pw = BW[a], ph = BH[a];
    float phw = pw*0.5f, phh = ph*0.5f;
    float wx = fmaxf(fminf(cx+hw, px+phw) - fmaxf(cx-hw, px-phw), 0.f);
    float wy = fmaxf(fminf(cy+hh, py+phh) - fmaxf(cy-hh, py-phh), 0.f);
    float inter = wx*wy;
    float iou = inter / fmaxf(gArea + pw*ph - inter, 1e-6f);
    float z = *chan_ptr(p8, p16, p32, b, a, ch);
    float clsc = -z - SL[a];                // logit identity, no exp/log
    float cost = clsc + 3.f*(-logf(iou + 1e-8f)) + (andm ? 0.f : BIGF);
    {   // lexicographic (cost, idx) insertion — order-independent & stable
      float v = cost; int vi = a;
      #pragma unroll
      for (int k = 0; k < 10; k++){
        if (v < lc[k] || (v == lc[k] && (unsigned)vi < (unsigned)li[k])){
          float tv = lc[k]; int ti = li[k];
          lc[k] = v; li[k] = vi; v = tv; vi = ti;
        }
      }
    }
    if (iou > lio[9]){
      float v = iou;
      #pragma unroll
      for (int k = 0; k < 10; k++){
        if (v > lio[k]){ float tv = lio[k]; lio[k] = v; v = tv; }
      }
    }
  }

  // ---- wave-level merge (no barriers): 10 rounds of 64-lane butterfly
  float mc[10]; int mi[10]; float mio[10];
  {
    int hp = 0;
    #pragma unroll
    for (int r = 0; r < 10; r++){
      float v  = (hp < 10) ? lc[hp] : 3.4e38f;
      int  idx = (hp < 10) ? li[hp] : -1;
      int  wl  = lane;
      #pragma unroll
      for (int s2 = 32; s2 > 0; s2 >>= 1){
        float v2 = __shfl_xor(v, s2, 64);
        int   i2 = __shfl_xor(idx, s2, 64);
        int   l2 = __shfl_xor(wl, s2, 64);
        if (v2 < v || (v2 == v && (unsigned)i2 < (unsigned)idx)){
          v = v2; idx = i2; wl = l2;
        }
      }
      mc[r] = v; mi[r] = idx;
      if (lane == wl) hp++;
    }
    int hq = 0;
    #pragma unroll
    for (int r = 0; r < 10; r++){
      float v = (hq < 10) ? lio[hq] : -2.f;
      int  wl = lane;
      #pragma unroll
      for (int s2 = 32; s2 > 0; s2 >>= 1){
        float v2 = __shfl_xor(v, s2, 64);
        int   l2 = __shfl_xor(wl, s2, 64);
        if (v2 > v || (v2 == v && l2 < wl)){ v = v2; wl = l2; }
      }
      mio[r] = v;
      if (lane == wl) hq++;
    }
  }

  __shared__ float smc[4*10]; __shared__ int smi[4*10]; __shared__ float smio[4*10];
  if (lane == 0){
    #pragma unroll
    for (int k = 0; k < 10; k++){
      smc[wave*10+k] = mc[k]; smi[wave*10+k] = mi[k]; smio[wave*10+k] = mio[k];
    }
  }
  __syncthreads();

  if (t == 0){
    float k10 = 0.f;
    {
      int h[4] = {0,0,0,0};
      for (int r = 0; r < 10; r++){
        float v = -2.f; int w = -1;
        for (int q = 0; q < 4; q++){
          if (h[q] < 10){
            float vq = smio[q*10+h[q]];
            if (vq > v){ v = vq; w = q; }
          }
        }
        if (w >= 0) h[w]++;
        k10 += fmaxf(v, 0.f);               // iou*or_m: empties contribute 0
      }
    }
    int dk = (int)k10;
    if (dk < 1) dk = 1;
    int ub = and_cnt > 1 ? and_cnt : 1;
    if (dk > ub) dk = ub;
    int h[4] = {0,0,0,0};
    for (int r = 0; r < dk && r < 10; r++){
      float v = 3.4e38f; int idx = -1; int w = -1;
      for (int q = 0; q < 4; q++){
        if (h[q] < 10){
          float vq = smc[q*10+h[q]]; int iq = smi[q*10+h[q]];
          if (vq < v || (vq == v && (unsigned)iq < (unsigned)idx)){
            v = vq; idx = iq; w = q;
          }
        }
      }
      if (idx < 0) break;                   // fewer than dk or_m anchors
      h[w]++;
      atomicOr(&bits[(size_t)b*ATOT + idx], 1ull << g);
    }
  }
}

// ---- K-loss: lazy loads — only fg/overlap anchors (~1%) touch the box arrays
__global__ void k_loss(const float* __restrict__ p8, const float* __restrict__ p16,
                       const float* __restrict__ p32, const float* __restrict__ tgt,
                       const int* __restrict__ cidx,
                       const float* __restrict__ bx, const float* __restrict__ by,
                       const float* __restrict__ bw, const float* __restrict__ bh,
                       const float* __restrict__ obj, const float* __restrict__ slog,
                       const unsigned long long* __restrict__ bits,
                       float* __restrict__ partials){
  int b = blockIdx.y;
  int a = blockIdx.x*TPB + threadIdx.x;
  __shared__ float gcx[GSZ], gcy[GSZ], ggw[GSZ], ggh[GSZ], gval[GSZ];
  __shared__ int gci[GSZ];
  for (int k = threadIdx.x; k < GSZ; k += TPB){
    const float* T = tgt + ((size_t)b*GSZ + k)*CDIM;
    gcx[k] = T[0]; gcy[k] = T[1]; ggw[k] = T[2]; ggh[k] = T[3]; gval[k] = T[4];
    gci[k] = cidx[b*GSZ + k];
  }
  __syncthreads();

  float contrib = 0.f;
  if (a < ATOT){
    size_t t = (size_t)b*ATOT + a;
    unsigned long long m = bits[t];
    float o = clampp(obj[t]);
    if (m == 0ull){
      contrib = -logf(1.f - o);                   // background conf BCE only
    } else {
      float px = bx[t], py = by[t], pw = bw[t], ph = bh[t], sl = slog[t];
      if (__builtin_popcountll(m) > 1){
        float bestc = INFF; int bestg = 0;
        for (int g = 0; g < GSZ; g++){
          float c = INFF;
          if (gval[g] == 1.0f){
            float z = *chan_ptr(p8, p16, p32, b, a, 5+gci[g]);
            float iou, clsc; bool orm, andm;
            compute_pair(gcx[g], gcy[g], ggw[g], ggh[g], px, py, pw, ph, z, sl,
                         c, iou, orm, andm, clsc);
          }
          if (c < bestc){ bestc = c; bestg = g; }
        }
        m = 1ull << bestg;
      }
      contrib = -logf(o);                         // foreground conf BCE
      while (m){
        int g = __builtin_ctzll(m);
        m &= m - 1;
        float z = *chan_ptr(p8, p16, p32, b, a, 5+gci[g]);
        float c, iou, clsc; bool orm, andm;
        compute_pair(gcx[g], gcy[g], ggw[g], ggh[g], px, py, pw, ph, z, sl,
                     c, iou, orm, andm, clsc);
        contrib += clsc + 5.f*(1.f - iou*iou);    // l_cls + reg_weight*l_reg
      }
    }
  }

  // wave reduce, then 4 wave-sums via LDS, single global store (NO atomics)
  #pragma unroll
  for (int s2 = 32; s2 > 0; s2 >>= 1) contrib += __shfl_xor(contrib, s2, 64);
  __shared__ float wsum[4];
  if ((threadIdx.x & 63) == 0) wsum[threadIdx.x >> 6] = contrib;
  __syncthreads();
  if (threadIdx.x == 0)
    partials[blockIdx.y*GRIDX + blockIdx.x] = wsum[0]+wsum[1]+wsum[2]+wsum[3];
}

// ---- K-final: reduce 1056 partials + count valid gts + divide
__global__ void k_final(const float* __restrict__ partials,
                        const float* __restrict__ tgt, float* __restrict__ out){
  int t = threadIdx.x;
  float s = 0.f;
  for (int i = t; i < NPART; i += TPB) s += partials[i];
  int n = 0;
  for (int i = t; i < BSZ*GSZ; i += TPB)
    n += (tgt[(size_t)i*CDIM + 4] == 1.0f) ? 1 : 0;
  __shared__ float sh[TPB]; __shared__ int shn[TPB];
  sh[t] = s; shn[t] = n;
  __syncthreads();
  for (int st = TPB/2; st > 0; st >>= 1){
    if (t < st){ sh[t] += sh[t+st]; shn[t] += shn[t+st]; }
    __syncthreads();
  }
  if (t == 0){
    int nn = shn[0] < 1 ? 1 : shn[0];
    out[0] = sh[0] / (float)nn;
  }
}

extern "C" void kernel_launch(void* const* d_in, const int* in_sizes, int n_in,
                              void* d_out, int out_size, void* d_ws, size_t ws_size,
                              hipStream_t stream) {
  const float* p8  = (const float*)d_in[0];
  const float* p16 = (const float*)d_in[1];
  const float* p32 = (const float*)d_in[2];
  const float* tgt = (const float*)d_in[3];
  float* out = (float*)d_out;

  const size_t BA = (size_t)BSZ*ATOT;
  float* bx   = (float*)d_ws;
  float* by   = bx + BA;
  float* bw   = by + BA;
  float* bh   = bw + BA;
  float* obj  = bh + BA;
  float* slog = obj + BA;
  unsigned long long* bits = (unsigned long long*)(slog + BA);  // 16B-aligned
  int* cidx = (int*)(bits + BA);
  float* partials = (float*)(cidx + BSZ*GSZ);

  dim3 blk(TPB);
  k_prep  <<<dim3((BSZ*GSZ + TPB-1)/TPB), blk, 0, stream>>>(tgt, cidx);
  k_decode<<<dim3((unsigned)(BA/TPB)), blk, 0, stream>>>(p8, p16, p32,
                                                   bx, by, bw, bh, obj, slog, bits);
  k_assign<<<dim3(GSZ, BSZ), blk, 0, stream>>>(p8, p16, p32, tgt, cidx,
                                               bx, by, bw, bh, slog, bits);
  k_loss  <<<dim3(GRIDX, BSZ), blk, 0, stream>>>(p8, p16, p32, tgt, cidx,
                                               bx, by, bw, bh, obj, slog, bits, partials);
  k_final <<<1, blk, 0, stream>>>(partials, tgt, out);
}

// Round 10
// 184.771 us; speedup vs baseline: 1.4778x; 1.0214x over previous
//
#include <hip/hip_runtime.h>
#include <math.h>

#define BSZ  32
#define GSZ  50
#define ATOT 8400
#define NCLS 80
#define CDIM 85
#define TPB  256
#define GRIDX ((ATOT + TPB - 1) / TPB)      // 33
#define NPART (GRIDX * BSZ)                 // 1056
#define MAXC 512                            // max or_m candidates per (gt,img); bound ~456

#define EPSF 1e-7f
#define BIGF 100000.0f
#define INFF 1000000000.0f
#define IMGF 640.0f
#define DISF 20.0f        // 2.5 * stride(8)
#define LOGEPS_HI -15.942385f   // logf(2^-23) = ref log(1 - (1-eps)) floor

// fast-math device intrinsics: native v_exp_f32/v_log_f32 (~2 ulp), no OCML wrapper.
__device__ __forceinline__ float fexp(float x){ return __expf(x); }
__device__ __forceinline__ float flog(float x){ return __logf(x); }

__device__ __forceinline__ float sigm(float z){ return 1.0f/(1.0f+fexp(-z)); }
__device__ __forceinline__ float clampp(float s){ return fminf(fmaxf(s, EPSF), 1.f-EPSF); }
// log(1 - clip(sigmoid(z))) via softplus identity (exact in the unclamped range)
__device__ __forceinline__ float log1msig(float z){
  return fmaxf(-flog(1.f + fexp(z)), LOGEPS_HI);
}

__device__ __forceinline__ const float* chan_ptr(const float* __restrict__ p8,
                                                 const float* __restrict__ p16,
                                                 const float* __restrict__ p32,
                                                 int b, int a, int ch){
  if (a < 6400) return p8  + ((size_t)(b*CDIM + ch))*6400 + a;
  if (a < 8000) return p16 + ((size_t)(b*CDIM + ch))*1600 + (a-6400);
  return p32 + ((size_t)(b*CDIM + ch))*400 + (a-8000);
}

// cost/iou for one (gt, anchor) pair; clsc via logit identity: log(1-s)-log(s) = -z
__device__ __forceinline__ void compute_pair(
  float cx, float cy, float gw, float gh,
  float px, float py, float pw, float ph,
  float z, float slog,
  float& cost, float& iou, bool& orm, bool& andm, float& clsc)
{
  float hw = gw*0.5f, hh = gh*0.5f;
  bool cm = (px >= fmaxf(cx-DISF,0.f)) && (px <= fminf(cx+DISF,IMGF)) &&
            (py >= fmaxf(cy-DISF,0.f)) && (py <= fminf(cy+DISF,IMGF));
  bool im = (px >= fmaxf(cx-hw,0.f)) && (px <= fminf(cx+hw,IMGF)) &&
            (py >= fmaxf(cy-hh,0.f)) && (py <= fminf(cy+hh,IMGF));
  orm = cm || im;  andm = cm && im;
  float phw = pw*0.5f, phh = ph*0.5f;
  float wx = fmaxf(fminf(cx+hw, px+phw) - fmaxf(cx-hw, px-phw), 0.f);
  float wy = fmaxf(fminf(cy+hh, py+phh) - fmaxf(cy-hh, py-phh), 0.f);
  float inter = wx*wy;
  float uni   = gw*gh + pw*ph - inter;
  iou = inter / fmaxf(uni, 1e-6f);
  clsc = -z - slog;
  cost = clsc + 3.f*(-flog(iou + 1e-8f)) + (andm ? 0.f : BIGF);
}

// ---- K-prep: per-gt class index (one-hot argmax)
__global__ void k_prep(const float* __restrict__ tgt, int* __restrict__ cidx){
  int t = blockIdx.x*blockDim.x + threadIdx.x;
  if (t >= BSZ*GSZ) return;
  const float* T = tgt + (size_t)t*CDIM;
  int best = 0; float bv = T[5];
  for (int c = 1; c < NCLS; c++){
    float v = T[5+c];
    if (v > bv){ bv = v; best = c; }
  }
  cidx[t] = best;
}

// ---- K-decode: 4 threads per float4-group (each owns 20 cls channels + 1 box ch).
// Per-wave load pattern: 16 groups x 4 channels -> 4 segments of 256 B.
// [r6/r8 lessons: 8-thread split (128B segments) and streaming+LDS-atomics both
//  regressed; this layout is the best measured.]
__global__ void k_decode(const float* __restrict__ p8, const float* __restrict__ p16,
                         const float* __restrict__ p32,
                         float* __restrict__ bx, float* __restrict__ by,
                         float* __restrict__ bw, float* __restrict__ bh,
                         float* __restrict__ obj, float* __restrict__ slog,
                         unsigned long long* __restrict__ bits){
  int t = blockIdx.x*blockDim.x + threadIdx.x;   // exactly BSZ*ATOT threads
  int sub = t & 3;
  int g   = t >> 2;                               // float4-group id
  int b = g / (ATOT/4);
  int q = g % (ATOT/4);
  int a0 = q*4;                                   // level edges 6400/8000 are /4
  const float* base; int l; float fs; int aL;
  if (a0 < 6400){ base = p8;  l = 80; fs = 8.f;  aL = a0; }
  else if (a0 < 8000){ base = p16; l = 40; fs = 16.f; aL = a0-6400; }
  else { base = p32; l = 20; fs = 32.f; aL = a0-8000; }
  int l2 = l*l;
  int cs = l2 >> 2;                               // channel stride in float4
  const float4* p4 = (const float4*)(base + (size_t)b*CDIM*l2) + (aL >> 2);

  // partial slog over this sub's class channels (5+sub, step 4 -> 20 channels)
  float4 S = make_float4(0.f,0.f,0.f,0.f);
  for (int c = 5+sub; c < CDIM; c += 4){
    float4 v = p4[c*cs];
    S.x += log1msig(v.x); S.y += log1msig(v.y);
    S.z += log1msig(v.z); S.w += log1msig(v.w);
  }
  // reduce across the 4 consecutive lanes of this group (same wave: 4 | 64)
  #pragma unroll
  for (int m = 1; m <= 2; m <<= 1){
    S.x += __shfl_xor(S.x, m, 64);
    S.y += __shfl_xor(S.y, m, 64);
    S.z += __shfl_xor(S.z, m, 64);
    S.w += __shfl_xor(S.w, m, 64);
  }

  int i = aL / l, j = aL % l;
  float fi = (float)i;
  uint4 z4 = make_uint4(0u,0u,0u,0u);
  if (sub == 0){
    float4 v0 = p4[0];
    float4 v4 = p4[4*cs];
    ((float4*)bx)[g]  = make_float4(((float)(j  )+sigm(v0.x))*fs, ((float)(j+1)+sigm(v0.y))*fs,
                                    ((float)(j+2)+sigm(v0.z))*fs, ((float)(j+3)+sigm(v0.w))*fs);
    ((float4*)obj)[g] = make_float4(sigm(v4.x), sigm(v4.y), sigm(v4.z), sigm(v4.w));
    ((uint4*)bits)[2*g] = z4;                     // zero 2 of 4 u64 masks
  } else if (sub == 1){
    float4 v1 = p4[cs];
    ((float4*)by)[g]   = make_float4((fi+sigm(v1.x))*fs, (fi+sigm(v1.y))*fs,
                                     (fi+sigm(v1.z))*fs, (fi+sigm(v1.w))*fs);
    ((float4*)slog)[g] = S;
  } else if (sub == 2){
    float4 v2 = p4[2*cs];
    ((float4*)bw)[g] = make_float4(fexp(v2.x)*fs, fexp(v2.y)*fs, fexp(v2.z)*fs, fexp(v2.w)*fs);
    ((uint4*)bits)[2*g+1] = z4;
  } else {
    float4 v3 = p4[3*cs];
    ((float4*)bh)[g] = make_float4(fexp(v3.x)*fs, fexp(v3.y)*fs, fexp(v3.z)*fs, fexp(v3.w)*fs);
  }
}

// ---- K-assign: one block per (gt g, image b); two-phase LDS compaction
__global__ void k_assign(const float* __restrict__ p8, const float* __restrict__ p16,
                         const float* __restrict__ p32, const float* __restrict__ tgt,
                         const int* __restrict__ cidx,
                         const float* __restrict__ bx, const float* __restrict__ by,
                         const float* __restrict__ bw, const float* __restrict__ bh,
                         const float* __restrict__ slog,
                         unsigned long long* __restrict__ bits){
  int g = blockIdx.x, b = blockIdx.y;
  const float* T = tgt + ((size_t)b*GSZ + g)*CDIM;
  if (T[4] != 1.0f) return;                 // uniform for whole block
  float cx = T[0], cy = T[1], gw = T[2], gh = T[3];
  float hw = gw*0.5f, hh = gh*0.5f;
  float cL = fmaxf(cx-DISF,0.f), cR = fminf(cx+DISF,IMGF);
  float cT = fmaxf(cy-DISF,0.f), cB = fminf(cy+DISF,IMGF);
  float iL = fmaxf(cx-hw,0.f),  iR = fminf(cx+hw,IMGF);
  float iT = fmaxf(cy-hh,0.f),  iB = fminf(cy+hh,IMGF);
  float gArea = gw*gh;
  int ch = 5 + cidx[b*GSZ + g];
  int t = threadIdx.x;
  int lane = t & 63, wave = t >> 6;

  const float* BX = bx + (size_t)b*ATOT;
  const float* BY = by + (size_t)b*ATOT;
  const float* BW = bw + (size_t)b*ATOT;
  const float* BH = bh + (size_t)b*ATOT;
  const float* SL = slog + (size_t)b*ATOT;

  // ---- phase A: mask-only scan, compact or_m candidates into LDS
  __shared__ int cand[MAXC];
  __shared__ int ncand_sh, nand_sh;
  if (t == 0){ ncand_sh = 0; nand_sh = 0; }
  __syncthreads();
  for (int a = t; a < ATOT; a += TPB){
    float px = BX[a], py = BY[a];
    bool cm = (px >= cL) && (px <= cR) && (py >= cT) && (py <= cB);
    bool im = (px >= iL) && (px <= iR) && (py >= iT) && (py <= iB);
    if (cm || im){
      int pos = atomicAdd(&ncand_sh, 1);
      if (pos < MAXC) cand[pos] = a | ((cm && im) ? 0x10000 : 0);
      if (cm && im) atomicAdd(&nand_sh, 1);
    }
  }
  __syncthreads();
  int nc = ncand_sh < MAXC ? ncand_sh : MAXC;
  int and_cnt = nand_sh;

  // ---- phase B: dense candidate processing (all gathers issue in parallel)
  float lc[10]; int li[10]; float lio[10];
  #pragma unroll
  for (int k = 0; k < 10; k++){ lc[k] = 3.0e38f; li[k] = -1; lio[k] = -1.f; }

  for (int c = t; c < nc; c += TPB){
    int packed = cand[c];
    int a = packed & 0xFFFF;
    bool andm = (packed & 0x10000) != 0;
    float px = BX[a], py = BY[a];
    float pw = BW[a], ph = BH[a];
    float phw = pw*0.5f, phh = ph*0.5f;
    float wx = fmaxf(fminf(cx+hw, px+phw) - fmaxf(cx-hw, px-phw), 0.f);
    float wy = fmaxf(fminf(cy+hh, py+phh) - fmaxf(cy-hh, py-phh), 0.f);
    float inter = wx*wy;
    float iou = inter / fmaxf(gArea + pw*ph - inter, 1e-6f);
    float z = *chan_ptr(p8, p16, p32, b, a, ch);
    float clsc = -z - SL[a];                // logit identity, no exp/log
    float cost = clsc + 3.f*(-flog(iou + 1e-8f)) + (andm ? 0.f : BIGF);
    {   // lexicographic (cost, idx) insertion — order-independent & stable
      float v = cost; int vi = a;
      #pragma unroll
      for (int k = 0; k < 10; k++){
        if (v < lc[k] || (v == lc[k] && (unsigned)vi < (unsigned)li[k])){
          float tv = lc[k]; int ti = li[k];
          lc[k] = v; li[k] = vi; v = tv; vi = ti;
        }
      }
    }
    if (iou > lio[9]){
      float v = iou;
      #pragma unroll
      for (int k = 0; k < 10; k++){
        if (v > lio[k]){ float tv = lio[k]; lio[k] = v; v = tv; }
      }
    }
  }

  // ---- wave-level merge (no barriers): 10 rounds of 64-lane butterfly
  float mc[10]; int mi[10]; float mio[10];
  {
    int hp = 0;
    #pragma unroll
    for (int r = 0; r < 10; r++){
      float v  = (hp < 10) ? lc[hp] : 3.4e38f;
      int  idx = (hp < 10) ? li[hp] : -1;
      int  wl  = lane;
      #pragma unroll
      for (int s2 = 32; s2 > 0; s2 >>= 1){
        float v2 = __shfl_xor(v, s2, 64);
        int   i2 = __shfl_xor(idx, s2, 64);
        int   l2 = __shfl_xor(wl, s2, 64);
        if (v2 < v || (v2 == v && (unsigned)i2 < (unsigned)idx)){
          v = v2; idx = i2; wl = l2;
        }
      }
      mc[r] = v; mi[r] = idx;
      if (lane == wl) hp++;
    }
    int hq = 0;
    #pragma unroll
    for (int r = 0; r < 10; r++){
      float v = (hq < 10) ? lio[hq] : -2.f;
      int  wl = lane;
      #pragma unroll
      for (int s2 = 32; s2 > 0; s2 >>= 1){
        float v2 = __shfl_xor(v, s2, 64);
        int   l2 = __shfl_xor(wl, s2, 64);
        if (v2 > v || (v2 == v && l2 < wl)){ v = v2; wl = l2; }
      }
      mio[r] = v;
      if (lane == wl) hq++;
    }
  }

  __shared__ float smc[4*10]; __shared__ int smi[4*10]; __shared__ float smio[4*10];
  if (lane == 0){
    #pragma unroll
    for (int k = 0; k < 10; k++){
      smc[wave*10+k] = mc[k]; smi[wave*10+k] = mi[k]; smio[wave*10+k] = mio[k];
    }
  }
  __syncthreads();

  if (t == 0){
    float k10 = 0.f;
    {
      int h[4] = {0,0,0,0};
      for (int r = 0; r < 10; r++){
        float v = -2.f; int w = -1;
        for (int q = 0; q < 4; q++){
          if (h[q] < 10){
            float vq = smio[q*10+h[q]];
            if (vq > v){ v = vq; w = q; }
          }
        }
        if (w >= 0) h[w]++;
        k10 += fmaxf(v, 0.f);               // iou*or_m: empties contribute 0
      }
    }
    int dk = (int)k10;
    if (dk < 1) dk = 1;
    int ub = and_cnt > 1 ? and_cnt : 1;
    if (dk > ub) dk = ub;
    int h[4] = {0,0,0,0};
    for (int r = 0; r < dk && r < 10; r++){
      float v = 3.4e38f; int idx = -1; int w = -1;
      for (int q = 0; q < 4; q++){
        if (h[q] < 10){
          float vq = smc[q*10+h[q]]; int iq = smi[q*10+h[q]];
          if (vq < v || (vq == v && (unsigned)iq < (unsigned)idx)){
            v = vq; idx = iq; w = q;
          }
        }
      }
      if (idx < 0) break;                   // fewer than dk or_m anchors
      h[w]++;
      atomicOr(&bits[(size_t)b*ATOT + idx], 1ull << g);
    }
  }
}

// ---- K-loss: lazy loads — only fg/overlap anchors (~1%) touch the box arrays
__global__ void k_loss(const float* __restrict__ p8, const float* __restrict__ p16,
                       const float* __restrict__ p32, const float* __restrict__ tgt,
                       const int* __restrict__ cidx,
                       const float* __restrict__ bx, const float* __restrict__ by,
                       const float* __restrict__ bw, const float* __restrict__ bh,
                       const float* __restrict__ obj, const float* __restrict__ slog,
                       const unsigned long long* __restrict__ bits,
                       float* __restrict__ partials){
  int b = blockIdx.y;
  int a = blockIdx.x*TPB + threadIdx.x;
  __shared__ float gcx[GSZ], gcy[GSZ], ggw[GSZ], ggh[GSZ], gval[GSZ];
  __shared__ int gci[GSZ];
  for (int k = threadIdx.x; k < GSZ; k += TPB){
    const float* T = tgt + ((size_t)b*GSZ + k)*CDIM;
    gcx[k] = T[0]; gcy[k] = T[1]; ggw[k] = T[2]; ggh[k] = T[3]; gval[k] = T[4];
    gci[k] = cidx[b*GSZ + k];
  }
  __syncthreads();

  float contrib = 0.f;
  if (a < ATOT){
    size_t t = (size_t)b*ATOT + a;
    unsigned long long m = bits[t];
    float o = clampp(obj[t]);
    if (m == 0ull){
      contrib = -flog(1.f - o);                   // background conf BCE only
    } else {
      float px = bx[t], py = by[t], pw = bw[t], ph = bh[t], sl = slog[t];
      if (__builtin_popcountll(m) > 1){
        float bestc = INFF; int bestg = 0;
        for (int g = 0; g < GSZ; g++){
          float c = INFF;
          if (gval[g] == 1.0f){
            float z = *chan_ptr(p8, p16, p32, b, a, 5+gci[g]);
            float iou, clsc; bool orm, andm;
            compute_pair(gcx[g], gcy[g], ggw[g], ggh[g], px, py, pw, ph, z, sl,
                         c, iou, orm, andm, clsc);
          }
          if (c < bestc){ bestc = c; bestg = g; }
        }
        m = 1ull << bestg;
      }
      contrib = -flog(o);                         // foreground conf BCE
      while (m){
        int g = __builtin_ctzll(m);
        m &= m - 1;
        float z = *chan_ptr(p8, p16, p32, b, a, 5+gci[g]);
        float c, iou, clsc; bool orm, andm;
        compute_pair(gcx[g], gcy[g], ggw[g], ggh[g], px, py, pw, ph, z, sl,
                     c, iou, orm, andm, clsc);
        contrib += clsc + 5.f*(1.f - iou*iou);    // l_cls + reg_weight*l_reg
      }
    }
  }

  // wave reduce, then 4 wave-sums via LDS, single global store (NO atomics)
  #pragma unroll
  for (int s2 = 32; s2 > 0; s2 >>= 1) contrib += __shfl_xor(contrib, s2, 64);
  __shared__ float wsum[4];
  if ((threadIdx.x & 63) == 0) wsum[threadIdx.x >> 6] = contrib;
  __syncthreads();
  if (threadIdx.x == 0)
    partials[blockIdx.y*GRIDX + blockIdx.x] = wsum[0]+wsum[1]+wsum[2]+wsum[3];
}

// ---- K-final: reduce 1056 partials + count valid gts + divide
__global__ void k_final(const float* __restrict__ partials,
                        const float* __restrict__ tgt, float* __restrict__ out){
  int t = threadIdx.x;
  float s = 0.f;
  for (int i = t; i < NPART; i += TPB) s += partials[i];
  int n = 0;
  for (int i = t; i < BSZ*GSZ; i += TPB)
    n += (tgt[(size_t)i*CDIM + 4] == 1.0f) ? 1 : 0;
  __shared__ float sh[TPB]; __shared__ int shn[TPB];
  sh[t] = s; shn[t] = n;
  __syncthreads();
  for (int st = TPB/2; st > 0; st >>= 1){
    if (t < st){ sh[t] += sh[t+st]; shn[t] += shn[t+st]; }
    __syncthreads();
  }
  if (t == 0){
    int nn = shn[0] < 1 ? 1 : shn[0];
    out[0] = sh[0] / (float)nn;
  }
}

extern "C" void kernel_launch(void* const* d_in, const int* in_sizes, int n_in,
                              void* d_out, int out_size, void* d_ws, size_t ws_size,
                              hipStream_t stream) {
  const float* p8  = (const float*)d_in[0];
  const float* p16 = (const float*)d_in[1];
  const float* p32 = (const float*)d_in[2];
  const float* tgt = (const float*)d_in[3];
  float* out = (float*)d_out;

  const size_t BA = (size_t)BSZ*ATOT;
  float* bx   = (float*)d_ws;
  float* by   = bx + BA;
  float* bw   = by + BA;
  float* bh   = bw + BA;
  float* obj  = bh + BA;
  float* slog = obj + BA;
  unsigned long long* bits = (unsigned long long*)(slog + BA);  // 16B-aligned
  int* cidx = (int*)(bits + BA);
  float* partials = (float*)(cidx + BSZ*GSZ);

  dim3 blk(TPB);
  k_prep  <<<dim3((BSZ*GSZ + TPB-1)/TPB), blk, 0, stream>>>(tgt, cidx);
  k_decode<<<dim3((unsigned)(BA/TPB)), blk, 0, stream>>>(p8, p16, p32,
                                                   bx, by, bw, bh, obj, slog, bits);
  k_assign<<<dim3(GSZ, BSZ), blk, 0, stream>>>(p8, p16, p32, tgt, cidx,
                                               bx, by, bw, bh, slog, bits);
  k_loss  <<<dim3(GRIDX, BSZ), blk, 0, stream>>>(p8, p16, p32, tgt, cidx,
                                               bx, by, bw, bh, obj, slog, bits, partials);
  k_final <<<1, blk, 0, stream>>>(partials, tgt, out);
}